// Round 5
// baseline (403.260 us; speedup 1.0000x reference)
//
#include <hip/hip_runtime.h>

// Problem constants (B=8, S=256, F=16384, K=32)
#define N_ELEMS  33554432   // 8*256*16384
#define N_TOKENS 2048
#define F4       4096       // float4 per token
#define K_TOTAL  65536u     // K * B * S
#define NBINS    4096       // fine bins over key range [0xC0000000, 0xC1000000) == f in [2,8)

// ws layout (uint32 word indices)
#define C_WINTH    4097     // winner threshold (key >= -> definitely selected)
#define C_CANDTH   4098     // candidate threshold (cutoff-bin lower edge)
#define C_NEED     4099     // how many to take from the cutoff bin
#define C_FB       4100     // fallback flag
#define C_N2       4101     // cutoff-bin candidate counter
#define C_DONE     4102     // k_main done-block counter
#define C_DONE2    4103     // k_finish done-block counter
#define N_CTR_END  4160

#define CNT_OFF    4608u    // per-token kept-gated count (2048 words, plain stores)
#define GLIST_OFF  8192u    // per-token OWNED regions: tok*GBUF uint2 entries (16 MiB)
#define GBUF       1024u    // per-token capacity (expected ~373; overflow -> fallback)
#define LIST2_OFF  (GLIST_OFF + 2u*GBUF*N_TOKENS)
#define CAP2       4096u    // cutoff-bin candidates (expected ~190)
#define FB1_OFF    16777216u  // fallback scratch lists (correctness-only path)
#define CAPF       2097152u
#define FB2_OFF    (FB1_OFF + 2u*CAPF)

#define FIN_BLOCKS 512      // k_finish grid

// Order-preserving fp32 -> u32 map (larger float <=> larger key)
__device__ __forceinline__ unsigned keyOf(float f) {
    unsigned b = __float_as_uint(f);
    return b ^ ((unsigned)((int)b >> 31) | 0x80000000u);
}
__device__ __forceinline__ float valOf(unsigned u) {
    unsigned b = (u & 0x80000000u) ? (u ^ 0x80000000u) : ~u;
    return __uint_as_float(b);
}
__device__ __forceinline__ unsigned umaxu(unsigned a, unsigned b) { return a > b ? a : b; }
__device__ __forceinline__ unsigned aload(const unsigned* p) {
    return __hip_atomic_load(p, __ATOMIC_RELAXED, __HIP_MEMORY_SCOPE_AGENT);
}

// ---------------- init: zero fine bins + counters (poison -> known state).
// Unavoidable as a separate dispatch: every cross-block accumulator/done-counter
// needs a known initial value before any producer can touch it.
__global__ void k_init(unsigned* __restrict__ ws) {
    int t = blockIdx.x * 256 + threadIdx.x;
    if (t < N_CTR_END) ws[t] = 0u;
}

// ---------------- main: ONE streaming pass over x/out (the only full-size
// traffic). Per token block: read 64 KB of x (8 float4/thread, straight-line),
// write 64 KB of zeros, LDS fine-hist, compact gated (f>=2) elements into the
// token's OWNED glist region (no global atomics in the hot loop). Last-
// finishing block (done-counter; others exit, no spinning) suffix-scans the
// merged bins and publishes thresholds + need + fallback flag.
__global__ __launch_bounds__(512) void k_main(const float4* __restrict__ x,
                                              const int* __restrict__ mask,
                                              unsigned* __restrict__ ws,
                                              float4* __restrict__ out) {
    __shared__ unsigned lh[NBINS];     // 16 KB; reused as scan buffer by last block
    __shared__ unsigned s_cnt, s_flag, s_b1, s_ka, s_found;
    const int tok = blockIdx.x;
    const int tid = threadIdx.x;
    const bool live = mask[tok] != 0;
    float4* ot = out + (size_t)tok * F4;
    const float4 z = make_float4(0.f, 0.f, 0.f, 0.f);
    for (int b = tid; b < NBINS; b += 512) lh[b] = 0u;
    if (tid == 0) s_cnt = 0u;
    __syncthreads();
    uint2* gseg = (uint2*)(ws + GLIST_OFF) + (size_t)tok * GBUF;
    if (live) {
        const float4* xt = x + (size_t)tok * F4;
        const unsigned baseIdx = (unsigned)tok * 16384u;
        float4 v[8];
        #pragma unroll
        for (int k = 0; k < 8; ++k) v[k] = xt[tid + k * 512];   // 8 loads in flight
        #pragma unroll
        for (int k = 0; k < 8; ++k) ot[tid + k * 512] = z;      // fused dense zero
        #pragma unroll
        for (int k = 0; k < 8; ++k) {
            const float ff[4] = {v[k].x, v[k].y, v[k].z, v[k].w};
            #pragma unroll
            for (int c = 0; c < 4; ++c) {
                float f = ff[c];
                if (f >= 2.0f) {       // ~2.3% of elements; cutoff ~2.66 for this input
                    unsigned u = keyOf(f);
                    unsigned bin = (u - 0xC0000000u) >> 12;
                    if (bin > 4095u) bin = 4095u;   // f>=8 clamps to top bin
                    atomicAdd(&lh[bin], 1u);
                    unsigned slot = atomicAdd(&s_cnt, 1u);
                    if (slot < GBUF)   // overflow: dropped, FB flagged below
                        gseg[slot] = make_uint2(u, baseIdx + ((unsigned)tid + (unsigned)k * 512u) * 4u + (unsigned)c);
                }
            }
        }
    } else {
        #pragma unroll
        for (int k = 0; k < 8; ++k) ot[tid + k * 512] = z;      // masked: zeros only
    }
    __syncthreads();
    unsigned cnt = s_cnt;
    const bool ovf = cnt > GBUF;
    if (ovf) cnt = GBUF;
    if (tid == 0) {
        ws[CNT_OFF + (unsigned)tok] = cnt;       // plain store to owned slot
        if (ovf) atomicOr(&ws[C_FB], 1u);        // pathological token -> exact fallback
    }
    if (live) {
        for (int b = tid; b < NBINS; b += 512) {
            unsigned c = lh[b];
            if (c) atomicAdd(&ws[b], c);         // ~350 nonzero bins/block (measured ~free)
        }
    }
    // ---- done-counter: last-finishing block runs the scan; others exit.
    __syncthreads();
    if (tid == 0) {
        __threadfence();                         // merges + cnt visible before done
        unsigned d = atomicAdd(&ws[C_DONE], 1u);
        s_flag = (d == (unsigned)(N_TOKENS - 1)) ? 1u : 0u;
    }
    __syncthreads();
    if (!s_flag) return;
    // ---- last block: suffix-scan 4096 bins (8 per thread; agent loads: bins
    // were written by device atomics from other XCDs).
    unsigned vv[8]; unsigned s = 0u;
    #pragma unroll
    for (int j = 0; j < 8; ++j) { vv[j] = aload(&ws[tid * 8 + j]); s += vv[j]; }
    unsigned* sc = lh;                 // reuse (hist merged already)
    if (tid == 0) s_found = 0u;
    sc[tid] = s;
    __syncthreads();
    for (int off = 1; off < 512; off <<= 1) {
        unsigned a = sc[tid];
        unsigned b2 = (tid + off < 512) ? sc[tid + off] : 0u;
        __syncthreads();
        sc[tid] = a + b2;              // sc[t] = cntGE(bin 8t)
        __syncthreads();
    }
    unsigned run = (tid < 511) ? sc[tid + 1] : 0u;   // cntGE(first bin of next chunk)
    #pragma unroll
    for (int j = 7; j >= 0; --j) {
        unsigned prev = run; run += vv[j];           // run = cntGE(bin 8t+j)
        if (run >= K_TOTAL && prev < K_TOTAL) {      // unique crossing
            s_b1 = (unsigned)(tid * 8 + j); s_ka = prev; s_found = 1u;
        }
    }
    __syncthreads();
    if (tid == 0) {
        unsigned total = sc[0];
        unsigned prevFB = aload(&ws[C_FB]);
        unsigned fb = prevFB | (((s_found == 0u) || (total < K_TOTAL) || (s_b1 == 4095u)) ? 1u : 0u);
        ws[C_FB] = fb;
        if (!fb) {
            unsigned candTh = 0xC0000000u + (s_b1 << 12);
            ws[C_CANDTH] = candTh;
            ws[C_WINTH]  = candTh + 0x1000u;
            ws[C_NEED]   = K_TOTAL - s_ka;
        }
    }
}

// ---------------- finish: grid-stride over the per-token glist regions
// (cache-hot, ~3 MB live): definite winners (>= winTh) written immediately;
// cutoff-bin candidates collected to list2. Last-finishing block: exact rank
// among ~190 candidates -> write the `need` selected + EMA threshold; or the
// full exact fallback inline (correctness-only; never runs for this input).
__global__ __launch_bounds__(512) void k_finish(const float4* __restrict__ x,
                                                const int* __restrict__ mask,
                                                unsigned* __restrict__ ws,
                                                float* __restrict__ out,
                                                const float* __restrict__ thr) {
    // LDS union: fast ent[4096]uint2 (32 KB) | fb lh[4096]+sred[512] (18 KB)
    __shared__ __align__(16) unsigned smem[8192];
    __shared__ unsigned s_last, s_pk;
    __shared__ unsigned sB1, sKA, sMode, sNegmin, sB2, sNeed, sCnt;
    const int t = threadIdx.x;
    const unsigned fb0 = ws[C_FB];     // cross-dispatch: plain load fine
    if (!fb0) {
        const unsigned winTh = ws[C_WINTH], candTh = ws[C_CANDTH];
        const uint2* glist = (const uint2*)(ws + GLIST_OFF);
        uint2* list2 = (uint2*)(ws + LIST2_OFF);
        for (unsigned tok = blockIdx.x; tok < N_TOKENS; tok += FIN_BLOCKS) {
            const unsigned cnt = ws[CNT_OFF + tok];
            const uint2* gseg = glist + (size_t)tok * GBUF;
            for (unsigned i = (unsigned)t; i < cnt; i += 512u) {
                uint2 e = gseg[i];
                if (e.x >= winTh) out[e.y] = valOf(e.x);     // >= 2.0 > 0: relu moot
                else if (e.x >= candTh) {                    // cutoff bin (~190 total)
                    unsigned g = atomicAdd(&ws[C_N2], 1u);
                    if (g < CAP2) list2[g] = e;
                }
            }
        }
    }
    __syncthreads();
    if (t == 0) {
        __threadfence();
        unsigned d = atomicAdd(&ws[C_DONE2], 1u);
        s_last = (d == FIN_BLOCKS - 1u) ? 1u : 0u;
    }
    __syncthreads();
    if (!s_last) return;

    const unsigned n2 = aload(&ws[C_N2]);
    if (!fb0 && n2 <= CAP2) {
        // ---- fast tail: exact rank among cutoff-bin candidates + EMA
        uint2* ent = (uint2*)smem;
        const unsigned need = ws[C_NEED];          // 1 <= need <= n2 by construction
        const unsigned* l2w = ws + LIST2_OFF;
        for (unsigned i = (unsigned)t; i < n2; i += 512u)    // agent loads: cross-XCD writes
            ent[i] = make_uint2(aload(&l2w[2u*i]), aload(&l2w[2u*i + 1u]));
        __syncthreads();
        for (unsigned i = (unsigned)t; i < n2; i += 512u) {
            uint2 e = ent[i];
            unsigned rank = 0u;
            for (unsigned j = 0; j < n2; ++j) {    // ties -> lower idx (jax.lax.top_k)
                uint2 o = ent[j];
                rank += (o.x > e.x || (o.x == e.x && o.y < e.y)) ? 1u : 0u;
            }
            if (rank < need) {
                out[e.y] = valOf(e.x);
                if (rank == need - 1u) s_pk = e.x; // pivot = min selected = min_pos
            }
        }
        __syncthreads();
        if (t == 0) out[N_ELEMS] = 0.99f * thr[0] + 0.01f * valOf(s_pk);
        return;
    }

    // ---- fallback: full exact algorithm (correctness-only). Out zeros are
    // already present from k_main; any winners already written above are true
    // top-k members (>= winTh => rank < K_TOTAL) and get rewritten identically.
    unsigned* lh = smem;               // [0, 4096): coarse 12-bit bins then reused
    unsigned* sred = smem + 4096;      // [4096, 4608)
    for (int b = t; b < NBINS; b += 512) lh[b] = 0u;
    if (t == 0) sCnt = 0u;
    __syncthreads();
    unsigned negmin = 0u;              // max(~key) over positive values
    for (int tok = 0; tok < N_TOKENS; ++tok) {
        if (!mask[tok]) continue;
        const float4* xt = x + (size_t)tok * F4;
        for (int j = t; j < F4; j += 512) {
            float4 v = xt[j];
            float fv[4] = {v.x, v.y, v.z, v.w};
            #pragma unroll
            for (int c = 0; c < 4; ++c) {
                float f = fv[c];
                unsigned u = keyOf(f);
                atomicAdd(&lh[u >> 20], 1u);
                if (f > 0.0f) negmin = umaxu(negmin, ~u);
            }
        }
    }
    __syncthreads();
    sred[t & 511] = 0u;  __syncthreads();
    sred[t] = negmin; __syncthreads();
    for (int off = 256; off > 0; off >>= 1) {
        if (t < off) sred[t] = umaxu(sred[t], sred[t + off]);
        __syncthreads();
    }
    if (t == 0) {
        sNegmin = sred[0];
        unsigned tot = 0u;
        for (int b = 0; b < NBINS; ++b) tot += lh[b];
        if (tot <= K_TOTAL) sMode = 1u;          // select ALL unmasked elements
        else {
            sMode = 0u;
            unsigned run = 0u, prev = 0u; int b1 = 0;
            for (int b = NBINS - 1; b >= 0; --b) {
                prev = run; run += lh[b];
                if (run >= K_TOTAL && prev < K_TOTAL) { b1 = b; break; }
            }
            sB1 = (unsigned)b1; sKA = prev;
        }
        sCnt = 0u;
    }
    __syncthreads();
    if (sMode == 1u) {
        for (int tok = 0; tok < N_TOKENS; ++tok) {
            if (!mask[tok]) continue;
            const float4* xt = x + (size_t)tok * F4;
            float* ot = out + (size_t)tok * 16384;
            for (int j = t; j < F4; j += 512) {
                float4 v = xt[j];
                ot[j * 4 + 0] = fmaxf(v.x, 0.f); ot[j * 4 + 1] = fmaxf(v.y, 0.f);
                ot[j * 4 + 2] = fmaxf(v.z, 0.f); ot[j * 4 + 3] = fmaxf(v.w, 0.f);
            }
        }
        if (t == 0) {
            float th = thr[0], newt = th;
            if (sNegmin) newt = 0.99f * th + 0.01f * valOf(~sNegmin);
            out[N_ELEMS] = newt;
        }
        return;
    }
    // phase 2: scatter coarse winners; compact coarse cutoff bin
    const unsigned B1c = sB1;
    uint2* fb1 = (uint2*)(ws + FB1_OFF);
    for (int tok = 0; tok < N_TOKENS; ++tok) {
        if (!mask[tok]) continue;
        const float4* xt = x + (size_t)tok * F4;
        const unsigned baseIdx = (unsigned)tok * 16384u;
        for (int j = t; j < F4; j += 512) {
            float4 v = xt[j];
            float fv[4] = {v.x, v.y, v.z, v.w};
            #pragma unroll
            for (int c = 0; c < 4; ++c) {
                float f = fv[c];
                unsigned u = keyOf(f);
                unsigned p = u >> 20;
                unsigned idx = baseIdx + (unsigned)j * 4u + (unsigned)c;
                if (p > B1c) out[idx] = fmaxf(f, 0.f);
                else if (p == B1c) {
                    unsigned g = atomicAdd(&sCnt, 1u);
                    if (g < CAPF) fb1[g] = make_uint2(u, idx);
                }
            }
        }
    }
    __syncthreads();
    unsigned n1 = sCnt > CAPF ? CAPF : sCnt;
    __syncthreads();
    if (t < 256) lh[t] = 0u;           // reuse as 8-bit refine histogram
    if (t == 0) sCnt = 0u;
    __syncthreads();
    for (unsigned i = t; i < n1; i += 512)
        atomicAdd(&lh[(fb1[i].x >> 12) & 255u], 1u);
    __syncthreads();
    if (t == 0) {
        unsigned run = sKA, prev = sKA; int b2 = 0;
        for (int b = 255; b >= 0; --b) {
            prev = run; run += lh[b];
            if (run >= K_TOTAL) { b2 = b; break; }
        }
        sB2 = (unsigned)b2; sNeed = K_TOTAL - prev;
    }
    __syncthreads();
    const unsigned B2 = sB2, need = sNeed;
    uint2* fb2 = (uint2*)(ws + FB2_OFF);
    for (unsigned i = t; i < n1; i += 512) {
        uint2 e = fb1[i];
        unsigned bb = (e.x >> 12) & 255u;
        if (bb > B2) out[e.y] = fmaxf(valOf(e.x), 0.f);
        else if (bb == B2) {
            unsigned g = atomicAdd(&sCnt, 1u);
            if (g < CAPF) fb2[g] = e;
        }
    }
    __syncthreads();
    unsigned n2f = sCnt > CAPF ? CAPF : sCnt;
    unsigned minSel = 0xFFFFFFFFu;
    for (unsigned i = t; i < n2f; i += 512) {
        uint2 e = fb2[i];
        unsigned rank = 0u;
        for (unsigned jj = 0; jj < n2f; ++jj) {
            uint2 o = fb2[jj];
            rank += (o.x > e.x || (o.x == e.x && o.y < e.y)) ? 1u : 0u;
        }
        if (rank < need) { out[e.y] = fmaxf(valOf(e.x), 0.f); if (e.x < minSel) minSel = e.x; }
    }
    __syncthreads();
    sred[t] = minSel; __syncthreads();
    for (int off = 256; off > 0; off >>= 1) {
        if (t < off) sred[t] = sred[t] < sred[t + off] ? sred[t] : sred[t + off];
        __syncthreads();
    }
    if (t == 0) {
        float th = thr[0], newt = th;
        unsigned vku = sred[0];
        if (vku != 0xFFFFFFFFu) {
            float vk = valOf(vku);
            float minpos; int any;
            if (vk > 0.f) { minpos = vk; any = 1; }
            else { any = (sNegmin != 0u); minpos = any ? valOf(~sNegmin) : 0.f; }
            if (any) newt = 0.99f * th + 0.01f * minpos;
        }
        out[N_ELEMS] = newt;
    }
}

extern "C" void kernel_launch(void* const* d_in, const int* in_sizes, int n_in,
                              void* d_out, int out_size, void* d_ws, size_t ws_size,
                              hipStream_t stream) {
    const float4* x  = (const float4*)d_in[0];
    const int* mask  = (const int*)d_in[1];
    const float* thr = (const float*)d_in[2];
    float* out       = (float*)d_out;
    unsigned* ws     = (unsigned*)d_ws;

    k_init   <<<17, 256, 0, stream>>>(ws);
    k_main   <<<N_TOKENS, 512, 0, stream>>>(x, mask, ws, (float4*)out);
    k_finish <<<FIN_BLOCKS, 512, 0, stream>>>(x, mask, ws, out, thr);
}

// Round 6
// 381.947 us; speedup vs baseline: 1.0558x; 1.0558x over previous
//
#include <hip/hip_runtime.h>

// Problem constants (B=8, S=256, F=16384, K=32)
#define N_ELEMS  33554432   // 8*256*16384
#define N4       8388608    // N_ELEMS/4
#define N_TOKENS 2048
#define F4       4096       // float4 per token
#define K_TOTAL  65536u     // K * B * S
#define NBINS    4096       // fine bins over key range [0xC0000000, 0xC1000000) == f in [2,8)

// ws layout (uint32 word indices)
#define C_NG       4096     // gated-list counter
#define C_WINTH    4097     // winner threshold (key >= -> definitely selected)
#define C_CANDTH   4098     // candidate threshold (cutoff-bin lower edge)
#define C_NEED     4099     // how many to take from the cutoff bin
#define C_FB       4100     // fallback flag
#define C_N2       4101     // cutoff-bin candidate counter
#define C_DONE     4102     // gate-block done counter
#define N_CTR_END  4160

#define GLIST_OFF  8192u    // uint2: all gated (f>=2) elements, (key, flat_idx)
#define CAPG       4194304u // expected ~380K; overflow -> fallback
#define LIST2_OFF  (GLIST_OFF + 2u*CAPG)
#define CAP2       4096u    // cutoff-bin candidates (expected ~190)
#define FB1_OFF    16777216u  // fallback scratch lists (correctness-only path)
#define CAPF       2097152u
#define FB2_OFF    (FB1_OFF + 2u*CAPF)

#define GBUF 1024           // per-block LDS staging for compaction
#define FILL_BLOCKS 1024    // 1024 fill blocks x 128 KB = 134 MB of zeros
#define STREAM_BLOCKS (N_TOKENS + FILL_BLOCKS)   // 3072

// Order-preserving fp32 -> u32 map (larger float <=> larger key)
__device__ __forceinline__ unsigned keyOf(float f) {
    unsigned b = __float_as_uint(f);
    return b ^ ((unsigned)((int)b >> 31) | 0x80000000u);
}
__device__ __forceinline__ float valOf(unsigned u) {
    unsigned b = (u & 0x80000000u) ? (u ^ 0x80000000u) : ~u;
    return __uint_as_float(b);
}
__device__ __forceinline__ unsigned umaxu(unsigned a, unsigned b) { return a > b ? a : b; }
__device__ __forceinline__ unsigned aload(const unsigned* p) {
    return __hip_atomic_load(p, __ATOMIC_RELAXED, __HIP_MEMORY_SCOPE_AGENT);
}

// ---------------- init: zero fine bins + counters (poison -> known state)
__global__ void k_init(unsigned* __restrict__ ws) {
    int t = blockIdx.x * 256 + threadIdx.x;
    if (t < N_CTR_END) ws[t] = 0u;
}

// ---------------- stream: ONE dispatch, TWO pure stream types (de-mixed at
// block level; interleaved b%3 so both co-run on every CU):
//   r<2  : gate block (token)  — PURE READ 64 KB of x, LDS fine-hist, compact
//          gated (f>=2) elems to glist via LDS staging (R2-proven inner shape).
//   r==2 : fill block          — PURE WRITE 128 KB of zeros to out (fill shape).
// Last-finishing gate block suffix-scans the merged bins and publishes
// thresholds + need + fallback flag (R5-proven done-counter fold).
__global__ __launch_bounds__(512) void k_stream(const float4* __restrict__ x,
                                                const int* __restrict__ mask,
                                                unsigned* __restrict__ ws,
                                                float4* __restrict__ out) {
    __shared__ unsigned lh[NBINS];     // 16 KB; reused as scan buffer by last gate block
    __shared__ uint2 sbuf[GBUF];       // 8 KB staging for compaction
    __shared__ unsigned s_cnt, s_base, s_flag, s_found, s_b1, s_ka;
    const int b = blockIdx.x;
    const int tid = threadIdx.x;
    const int r = b % 3;
    if (r == 2) {                      // ---- fill block: pure zero-store stream
        const int fid = b / 3;         // 0..1023
        float4* o = out + (size_t)fid * 8192;
        const float4 z = make_float4(0.f, 0.f, 0.f, 0.f);
        #pragma unroll
        for (int k = 0; k < 16; ++k) o[tid + k * 512] = z;
        return;
    }
    // ---- gate block
    const int tok = (b / 3) * 2 + r;   // 0..2047
    const bool live = mask[tok] != 0;
    uint2* glist = (uint2*)(ws + GLIST_OFF);
    if (tid == 0) s_cnt = 0u;
    if (live) {
        for (int bb = tid; bb < NBINS; bb += 512) lh[bb] = 0u;
        __syncthreads();
        const float4* xt = x + (size_t)tok * F4;
        const unsigned baseIdx = (unsigned)tok * 16384u;
        #pragma unroll
        for (int half = 0; half < 2; ++half) {   // 4 named loads in flight (R2-proven)
            const int j0 = tid + half * 2048;
            float4 v0 = xt[j0];
            float4 v1 = xt[j0 + 512];
            float4 v2 = xt[j0 + 1024];
            float4 v3 = xt[j0 + 1536];
            float fv[16] = {v0.x, v0.y, v0.z, v0.w, v1.x, v1.y, v1.z, v1.w,
                            v2.x, v2.y, v2.z, v2.w, v3.x, v3.y, v3.z, v3.w};
            #pragma unroll
            for (int c = 0; c < 16; ++c) {
                float f = fv[c];
                if (f >= 2.0f) {       // ~2.3% of elements; cutoff ~2.66 for this input
                    unsigned u = keyOf(f);
                    unsigned bin = (u - 0xC0000000u) >> 12;
                    if (bin > 4095u) bin = 4095u;    // f>=8 clamps to top bin
                    atomicAdd(&lh[bin], 1u);
                    unsigned slot = atomicAdd(&s_cnt, 1u);
                    unsigned j = (unsigned)(j0 + (c >> 2) * 512);
                    uint2 e = make_uint2(u, baseIdx + j * 4u + (unsigned)(c & 3));
                    if (slot < GBUF) sbuf[slot] = e;
                    else { unsigned g = atomicAdd(&ws[C_NG], 1u); if (g < CAPG) glist[g] = e; }
                }
            }
        }
        __syncthreads();
        for (int bb = tid; bb < NBINS; bb += 512) {
            unsigned c = lh[bb];
            if (c) atomicAdd(&ws[bb], c);        // ~350 nonzero bins/block
        }
        unsigned cnt = s_cnt; if (cnt > GBUF) cnt = GBUF;   // expected ~373/block
        if (tid == 0) s_base = atomicAdd(&ws[C_NG], cnt);   // one bulk atomic/block
        __syncthreads();
        for (unsigned j = tid; j < cnt; j += 512u) {
            unsigned p = s_base + j;
            if (p < CAPG) glist[p] = sbuf[j];
        }
    }
    // ---- done-counter: last-finishing gate block runs the scan; others exit.
    __syncthreads();
    if (tid == 0) {
        __threadfence();                         // merges + list visible before done
        unsigned d = atomicAdd(&ws[C_DONE], 1u);
        s_flag = (d == (unsigned)(N_TOKENS - 1)) ? 1u : 0u;
        s_found = 0u;
    }
    __syncthreads();
    if (!s_flag) return;
    // ---- last gate block: suffix-scan 4096 bins, 8/thread (agent loads:
    // bins were written by device atomics from other XCDs).
    unsigned vv[8]; unsigned s = 0u;
    #pragma unroll
    for (int j = 0; j < 8; ++j) { vv[j] = aload(&ws[tid * 8 + j]); s += vv[j]; }
    unsigned* sc = lh;                 // reuse (hist merged already; safe for masked too)
    sc[tid] = s;
    __syncthreads();
    for (int off = 1; off < 512; off <<= 1) {
        unsigned a = sc[tid];
        unsigned b2 = (tid + off < 512) ? sc[tid + off] : 0u;
        __syncthreads();
        sc[tid] = a + b2;              // sc[t] = cntGE(bin 8t)
        __syncthreads();
    }
    unsigned run = (tid < 511) ? sc[tid + 1] : 0u;   // cntGE(first bin of next chunk)
    #pragma unroll
    for (int j = 7; j >= 0; --j) {
        unsigned prev = run; run += vv[j];           // run = cntGE(bin 8t+j)
        if (run >= K_TOTAL && prev < K_TOTAL) {      // unique crossing
            s_b1 = (unsigned)(tid * 8 + j); s_ka = prev; s_found = 1u;
        }
    }
    __syncthreads();
    if (tid == 0) {
        unsigned total = sc[0];
        unsigned ngRaw = aload(&ws[C_NG]);
        unsigned fb = ((s_found == 0u) || (total < K_TOTAL) ||
                       (s_b1 == 4095u) || (ngRaw > CAPG)) ? 1u : 0u;
        ws[C_FB] = fb;
        if (!fb) {
            unsigned candTh = 0xC0000000u + (s_b1 << 12);
            ws[C_CANDTH] = candTh;
            ws[C_WINTH]  = candTh + 0x1000u;
            ws[C_NEED]   = K_TOTAL - s_ka;
        }
    }
}

// ---------------- scatter winners from the compact gated list (no x re-read,
// no scan — thresholds published by k_stream's last gate block).
__global__ __launch_bounds__(256) void k_scatter(unsigned* __restrict__ ws,
                                                 float* __restrict__ out) {
    if (ws[C_FB]) return;
    const unsigned winTh = ws[C_WINTH], candTh = ws[C_CANDTH];
    unsigned ng = ws[C_NG]; if (ng > CAPG) ng = CAPG;
    uint2* glist = (uint2*)(ws + GLIST_OFF);
    uint2* list2 = (uint2*)(ws + LIST2_OFF);
    const unsigned stride = gridDim.x * 256u;
    for (unsigned i = blockIdx.x * 256u + (unsigned)threadIdx.x; i < ng; i += stride) {
        uint2 e = glist[i];
        if (e.x >= winTh) out[e.y] = valOf(e.x);     // >= 2.0 > 0: relu moot
        else if (e.x >= candTh) {                    // cutoff bin (~190 total)
            unsigned g = atomicAdd(&ws[C_N2], 1u);
            if (g < CAP2) list2[g] = e;
        }
    }
}

// ---------------- tail + fallback merged (1 block, 1024 threads): fast path =
// exact rank among cutoff-bin candidates + EMA; else full exact fallback.
__global__ __launch_bounds__(1024) void k_tail(const float4* __restrict__ x,
                                               const int* __restrict__ mask,
                                               unsigned* __restrict__ ws,
                                               float* __restrict__ out,
                                               const float* __restrict__ thr) {
    // LDS union: tail ent[4096]uint2 + red[1024] | fb lh[4096]+sred[1024]
    __shared__ __align__(16) unsigned smem[9216];   // 36 KB
    __shared__ unsigned sB1, sKA, sMode, sNegmin, sB2, sNeed, sCnt;
    const int t = threadIdx.x;
    const unsigned rawn2 = ws[C_N2];
    const unsigned fb = ws[C_FB] | (rawn2 > CAP2 ? 1u : 0u);

    if (!fb) {
        // ---- fast tail: exact rank among cutoff-bin candidates + EMA threshold
        uint2* ent = (uint2*)smem;                 // [0, 8192) words
        unsigned* red = smem + 8192;               // [8192, 9216)
        const unsigned n2 = rawn2;
        const unsigned need = ws[C_NEED];          // >= 1 by crossing construction
        uint2* list2 = (uint2*)(ws + LIST2_OFF);
        for (unsigned i = (unsigned)t; i < n2; i += 1024u) ent[i] = list2[i];
        __syncthreads();
        unsigned minSel = 0xFFFFFFFFu;
        for (unsigned i = (unsigned)t; i < n2; i += 1024u) {
            uint2 e = ent[i];
            unsigned rank = 0u;
            for (unsigned j = 0; j < n2; ++j) {    // ties -> lower idx (jax.lax.top_k)
                uint2 o = ent[j];
                rank += (o.x > e.x || (o.x == e.x && o.y < e.y)) ? 1u : 0u;
            }
            if (rank < need) {
                out[e.y] = valOf(e.x);
                if (e.x < minSel) minSel = e.x;
            }
        }
        red[t] = minSel;
        __syncthreads();
        for (int off = 512; off > 0; off >>= 1) {
            if (t < off) red[t] = red[t] < red[t + off] ? red[t] : red[t + off];
            __syncthreads();
        }
        if (t == 0) {
            // fast path: min selected = k-th largest >= 2.0 > 0 == min_pos
            out[N_ELEMS] = 0.99f * thr[0] + 0.01f * valOf(red[0]);
        }
        return;
    }

    // ---- fallback: full exact algorithm (correctness-only; never runs for
    // this input — cutoff >= 2.0 with wide margin). Out zeros are already
    // present from k_stream's fill blocks.
    unsigned* lh = smem;               // [0, 4096): coarse 12-bit bins then reused
    unsigned* sred = smem + 4096;      // [4096, 5120)
    for (int b = t; b < NBINS; b += 1024) lh[b] = 0u;
    if (t == 0) sCnt = 0u;
    __syncthreads();
    unsigned negmin = 0u;              // max(~key) over positive values
    for (int tok = 0; tok < N_TOKENS; ++tok) {
        if (!mask[tok]) continue;
        const float4* xt = x + (size_t)tok * F4;
        for (int j = t; j < F4; j += 1024) {
            float4 v = xt[j];
            float fv[4] = {v.x, v.y, v.z, v.w};
            #pragma unroll
            for (int c = 0; c < 4; ++c) {
                float f = fv[c];
                unsigned u = keyOf(f);
                atomicAdd(&lh[u >> 20], 1u);
                if (f > 0.0f) negmin = umaxu(negmin, ~u);
            }
        }
    }
    __syncthreads();
    sred[t] = negmin; __syncthreads();
    for (int off = 512; off > 0; off >>= 1) {
        if (t < off) sred[t] = umaxu(sred[t], sred[t + off]);
        __syncthreads();
    }
    if (t == 0) {
        sNegmin = sred[0];
        unsigned tot = 0u;
        for (int b = 0; b < NBINS; ++b) tot += lh[b];
        if (tot <= K_TOTAL) sMode = 1u;          // select ALL unmasked elements
        else {
            sMode = 0u;
            unsigned run = 0u, prev = 0u; int b1 = 0;
            for (int b = NBINS - 1; b >= 0; --b) {
                prev = run; run += lh[b];
                if (run >= K_TOTAL && prev < K_TOTAL) { b1 = b; break; }
            }
            sB1 = (unsigned)b1; sKA = prev;
        }
        sCnt = 0u;
    }
    __syncthreads();
    if (sMode == 1u) {
        for (int tok = 0; tok < N_TOKENS; ++tok) {
            if (!mask[tok]) continue;
            const float4* xt = x + (size_t)tok * F4;
            float* ot = out + (size_t)tok * 16384;
            for (int j = t; j < F4; j += 1024) {
                float4 v = xt[j];
                ot[j * 4 + 0] = fmaxf(v.x, 0.f); ot[j * 4 + 1] = fmaxf(v.y, 0.f);
                ot[j * 4 + 2] = fmaxf(v.z, 0.f); ot[j * 4 + 3] = fmaxf(v.w, 0.f);
            }
        }
        if (t == 0) {
            float th = thr[0], newt = th;
            if (sNegmin) newt = 0.99f * th + 0.01f * valOf(~sNegmin);
            out[N_ELEMS] = newt;
        }
        return;
    }
    // phase 2: scatter coarse winners; compact coarse cutoff bin
    const unsigned B1c = sB1;
    uint2* fb1 = (uint2*)(ws + FB1_OFF);
    for (int tok = 0; tok < N_TOKENS; ++tok) {
        if (!mask[tok]) continue;
        const float4* xt = x + (size_t)tok * F4;
        const unsigned baseIdx = (unsigned)tok * 16384u;
        for (int j = t; j < F4; j += 1024) {
            float4 v = xt[j];
            float fv[4] = {v.x, v.y, v.z, v.w};
            #pragma unroll
            for (int c = 0; c < 4; ++c) {
                float f = fv[c];
                unsigned u = keyOf(f);
                unsigned p = u >> 20;
                unsigned idx = baseIdx + (unsigned)j * 4u + (unsigned)c;
                if (p > B1c) out[idx] = fmaxf(f, 0.f);
                else if (p == B1c) {
                    unsigned g = atomicAdd(&sCnt, 1u);
                    if (g < CAPF) fb1[g] = make_uint2(u, idx);
                }
            }
        }
    }
    __syncthreads();
    unsigned n1 = sCnt > CAPF ? CAPF : sCnt;
    __syncthreads();
    if (t < 256) lh[t] = 0u;           // reuse as 8-bit refine histogram
    if (t == 0) sCnt = 0u;
    __syncthreads();
    for (unsigned i = t; i < n1; i += 1024)
        atomicAdd(&lh[(fb1[i].x >> 12) & 255u], 1u);
    __syncthreads();
    if (t == 0) {
        unsigned run = sKA, prev = sKA; int b2 = 0;
        for (int b = 255; b >= 0; --b) {
            prev = run; run += lh[b];
            if (run >= K_TOTAL) { b2 = b; break; }
        }
        sB2 = (unsigned)b2; sNeed = K_TOTAL - prev;
    }
    __syncthreads();
    const unsigned B2 = sB2, need = sNeed;
    uint2* fb2 = (uint2*)(ws + FB2_OFF);
    for (unsigned i = t; i < n1; i += 1024) {
        uint2 e = fb1[i];
        unsigned bb = (e.x >> 12) & 255u;
        if (bb > B2) out[e.y] = fmaxf(valOf(e.x), 0.f);
        else if (bb == B2) {
            unsigned g = atomicAdd(&sCnt, 1u);
            if (g < CAPF) fb2[g] = e;
        }
    }
    __syncthreads();
    unsigned n2f = sCnt > CAPF ? CAPF : sCnt;
    unsigned minSel = 0xFFFFFFFFu;
    for (unsigned i = t; i < n2f; i += 1024) {
        uint2 e = fb2[i];
        unsigned rank = 0u;
        for (unsigned jj = 0; jj < n2f; ++jj) {
            uint2 o = fb2[jj];
            rank += (o.x > e.x || (o.x == e.x && o.y < e.y)) ? 1u : 0u;
        }
        if (rank < need) { out[e.y] = fmaxf(valOf(e.x), 0.f); if (e.x < minSel) minSel = e.x; }
    }
    __syncthreads();
    sred[t] = minSel; __syncthreads();
    for (int off = 512; off > 0; off >>= 1) {
        if (t < off) sred[t] = sred[t] < sred[t + off] ? sred[t] : sred[t + off];
        __syncthreads();
    }
    if (t == 0) {
        float th = thr[0], newt = th;
        unsigned vku = sred[0];
        if (vku != 0xFFFFFFFFu) {
            float vk = valOf(vku);
            float minpos; int any;
            if (vk > 0.f) { minpos = vk; any = 1; }
            else { any = (sNegmin != 0u); minpos = any ? valOf(~sNegmin) : 0.f; }
            if (any) newt = 0.99f * th + 0.01f * minpos;
        }
        out[N_ELEMS] = newt;
    }
}

extern "C" void kernel_launch(void* const* d_in, const int* in_sizes, int n_in,
                              void* d_out, int out_size, void* d_ws, size_t ws_size,
                              hipStream_t stream) {
    const float4* x  = (const float4*)d_in[0];
    const int* mask  = (const int*)d_in[1];
    const float* thr = (const float*)d_in[2];
    float* out       = (float*)d_out;
    unsigned* ws     = (unsigned*)d_ws;

    k_init    <<<17, 256, 0, stream>>>(ws);
    k_stream  <<<STREAM_BLOCKS, 512, 0, stream>>>(x, mask, ws, (float4*)out);
    k_scatter <<<512, 256, 0, stream>>>(ws, out);
    k_tail    <<<1, 1024, 0, stream>>>(x, mask, ws, out, thr);
}

// Round 8
// 272.525 us; speedup vs baseline: 1.4797x; 1.4015x over previous
//
#include <hip/hip_runtime.h>

// Problem constants (B=8, S=256, F=16384, K=32)
#define N_ELEMS  33554432   // 8*256*16384
#define N4       8388608    // N_ELEMS/4
#define N_TOKENS 2048
#define F4       4096       // float4 per token
#define K_TOTAL  65536u     // K * B * S
#define NBINS    4096       // fine bins over key range [0xC0000000, 0xC1000000) == f in [2,8)

// ws layout (uint32 word indices)
#define C_NG       4096     // gated-list counter
#define C_WINTH    4097     // winner threshold (key >= -> definitely selected)
#define C_CANDTH   4098     // candidate threshold (cutoff-bin lower edge)
#define C_NEED     4099     // how many to take from the cutoff bin
#define C_FB       4100     // fallback flag
#define C_N2       4101     // cutoff-bin candidate counter
#define C_DONE     4102     // gate-block done counter
#define N_CTR_END  4160

#define GLIST_OFF  8192u    // uint2: all gated (f>=2) elements, (key, flat_idx)
#define CAPG       4194304u // expected ~380K; overflow -> fallback
#define LIST2_OFF  (GLIST_OFF + 2u*CAPG)
#define CAP2       4096u    // cutoff-bin candidates (expected ~190)
#define FB1_OFF    16777216u  // fallback scratch lists (correctness-only path)
#define CAPF       2097152u
#define FB2_OFF    (FB1_OFF + 2u*CAPF)

#define GBUF 1024           // per-block LDS staging for compaction
#define FILL_BLOCKS 1024    // 1024 fill blocks x 128 KB = 134 MB of zeros
#define STREAM_BLOCKS (N_TOKENS + FILL_BLOCKS)   // 3072

// Native clang vector type for nontemporal builtins (HIP float4 is a class).
typedef float floatx4 __attribute__((ext_vector_type(4)));

// Order-preserving fp32 -> u32 map (larger float <=> larger key)
__device__ __forceinline__ unsigned keyOf(float f) {
    unsigned b = __float_as_uint(f);
    return b ^ ((unsigned)((int)b >> 31) | 0x80000000u);
}
__device__ __forceinline__ float valOf(unsigned u) {
    unsigned b = (u & 0x80000000u) ? (u ^ 0x80000000u) : ~u;
    return __uint_as_float(b);
}
__device__ __forceinline__ unsigned umaxu(unsigned a, unsigned b) { return a > b ? a : b; }
__device__ __forceinline__ unsigned aload(const unsigned* p) {
    return __hip_atomic_load(p, __ATOMIC_RELAXED, __HIP_MEMORY_SCOPE_AGENT);
}

// ---------------- init: zero fine bins + counters (poison -> known state)
__global__ void k_init(unsigned* __restrict__ ws) {
    int t = blockIdx.x * 256 + threadIdx.x;
    if (t < N_CTR_END) ws[t] = 0u;
}

// ---------------- stream: ONE dispatch, TWO pure stream types (de-mixed at
// block level; interleaved b%3 so both co-run on every CU):
//   r<2  : gate block (token)  — PURE READ 64 KB of x, LDS fine-hist, compact
//          gated (f>=2) elems to glist via LDS staging (R2-proven inner shape).
//   r==2 : fill block          — PURE WRITE 128 KB of zeros (nontemporal).
// Last-finishing gate block suffix-scans the merged bins and publishes
// thresholds + need + fallback flag.
// NO __threadfence here: on gfx950 a device fence = full L2 wb/inv walk;
// 2048 of them serialized k_stream at ~185 us (R5/R6 measured). Ordering my
// completed device-scope atomics before the done-increment needs only
// s_waitcnt vmcnt(0) — atomics complete at the coherent point, nothing dirty.
__global__ __launch_bounds__(512) void k_stream(const float4* __restrict__ x,
                                                const int* __restrict__ mask,
                                                unsigned* __restrict__ ws,
                                                float4* __restrict__ out) {
    __shared__ unsigned lh[NBINS];     // 16 KB; reused as scan buffer by last gate block
    __shared__ uint2 sbuf[GBUF];       // 8 KB staging for compaction
    __shared__ unsigned s_cnt, s_base, s_flag, s_found, s_b1, s_ka;
    const int b = blockIdx.x;
    const int tid = threadIdx.x;
    const int r = b % 3;
    if (r == 2) {                      // ---- fill block: pure zero-store stream
        const int fid = b / 3;         // 0..1023
        floatx4* o = (floatx4*)(out + (size_t)fid * 8192);
        const floatx4 z = (floatx4)0.f;
        #pragma unroll
        for (int k = 0; k < 16; ++k)
            __builtin_nontemporal_store(z, &o[tid + k * 512]);
        return;
    }
    // ---- gate block
    const int tok = (b / 3) * 2 + r;   // 0..2047
    const bool live = mask[tok] != 0;
    uint2* glist = (uint2*)(ws + GLIST_OFF);
    if (tid == 0) s_cnt = 0u;
    if (live) {
        for (int bb = tid; bb < NBINS; bb += 512) lh[bb] = 0u;
        __syncthreads();
        const float4* xt = x + (size_t)tok * F4;
        const unsigned baseIdx = (unsigned)tok * 16384u;
        #pragma unroll
        for (int half = 0; half < 2; ++half) {   // 4 named loads in flight (R2-proven)
            const int j0 = tid + half * 2048;
            float4 v0 = xt[j0];
            float4 v1 = xt[j0 + 512];
            float4 v2 = xt[j0 + 1024];
            float4 v3 = xt[j0 + 1536];
            float fv[16] = {v0.x, v0.y, v0.z, v0.w, v1.x, v1.y, v1.z, v1.w,
                            v2.x, v2.y, v2.z, v2.w, v3.x, v3.y, v3.z, v3.w};
            #pragma unroll
            for (int c = 0; c < 16; ++c) {
                float f = fv[c];
                if (f >= 2.0f) {       // ~2.3% of elements; cutoff ~2.66 for this input
                    unsigned u = keyOf(f);
                    unsigned bin = (u - 0xC0000000u) >> 12;
                    if (bin > 4095u) bin = 4095u;    // f>=8 clamps to top bin
                    atomicAdd(&lh[bin], 1u);
                    unsigned slot = atomicAdd(&s_cnt, 1u);
                    unsigned j = (unsigned)(j0 + (c >> 2) * 512);
                    uint2 e = make_uint2(u, baseIdx + j * 4u + (unsigned)(c & 3));
                    if (slot < GBUF) sbuf[slot] = e;
                    else { unsigned g = atomicAdd(&ws[C_NG], 1u); if (g < CAPG) glist[g] = e; }
                }
            }
        }
        __syncthreads();
        for (int bb = tid; bb < NBINS; bb += 512) {
            unsigned c = lh[bb];
            if (c) atomicAdd(&ws[bb], c);        // ~350 nonzero bins/block
        }
        unsigned cnt = s_cnt; if (cnt > GBUF) cnt = GBUF;   // expected ~373/block
        if (tid == 0) s_base = atomicAdd(&ws[C_NG], cnt);   // one bulk atomic/block
        __syncthreads();
        for (unsigned j = tid; j < cnt; j += 512u) {
            unsigned p = s_base + j;
            if (p < CAPG) glist[p] = sbuf[j];
        }
    }
    // ---- done-counter: last-finishing gate block runs the scan; others exit.
    __syncthreads();
    if (tid == 0) {
        // Wait for MY outstanding global ops (hist-merge atomics + glist
        // stores) to reach the coherent point, then signal. NOT a cache fence.
        asm volatile("s_waitcnt vmcnt(0)" ::: "memory");
        unsigned d = atomicAdd(&ws[C_DONE], 1u);
        s_flag = (d == (unsigned)(N_TOKENS - 1)) ? 1u : 0u;
        s_found = 0u;
    }
    __syncthreads();
    if (!s_flag) return;
    // ---- last gate block: suffix-scan 4096 bins, 8/thread (agent atomic
    // loads: bins were written by device atomics from other XCDs).
    unsigned vv[8]; unsigned s = 0u;
    #pragma unroll
    for (int j = 0; j < 8; ++j) { vv[j] = aload(&ws[tid * 8 + j]); s += vv[j]; }
    unsigned* sc = lh;                 // reuse (hist merged already; safe for masked too)
    sc[tid] = s;
    __syncthreads();
    for (int off = 1; off < 512; off <<= 1) {
        unsigned a = sc[tid];
        unsigned b2 = (tid + off < 512) ? sc[tid + off] : 0u;
        __syncthreads();
        sc[tid] = a + b2;              // sc[t] = cntGE(bin 8t)
        __syncthreads();
    }
    unsigned run = (tid < 511) ? sc[tid + 1] : 0u;   // cntGE(first bin of next chunk)
    #pragma unroll
    for (int j = 7; j >= 0; --j) {
        unsigned prev = run; run += vv[j];           // run = cntGE(bin 8t+j)
        if (run >= K_TOTAL && prev < K_TOTAL) {      // unique crossing
            s_b1 = (unsigned)(tid * 8 + j); s_ka = prev; s_found = 1u;
        }
    }
    __syncthreads();
    if (tid == 0) {
        unsigned total = sc[0];
        unsigned ngRaw = aload(&ws[C_NG]);
        unsigned fb = ((s_found == 0u) || (total < K_TOTAL) ||
                       (s_b1 == 4095u) || (ngRaw > CAPG)) ? 1u : 0u;
        ws[C_FB] = fb;
        if (!fb) {
            unsigned candTh = 0xC0000000u + (s_b1 << 12);
            ws[C_CANDTH] = candTh;
            ws[C_WINTH]  = candTh + 0x1000u;
            ws[C_NEED]   = K_TOTAL - s_ka;
        }
    }
}

// ---------------- scatter winners from the compact gated list (no x re-read,
// no scan — thresholds published by k_stream's last gate block).
__global__ __launch_bounds__(256) void k_scatter(unsigned* __restrict__ ws,
                                                 float* __restrict__ out) {
    if (ws[C_FB]) return;
    const unsigned winTh = ws[C_WINTH], candTh = ws[C_CANDTH];
    unsigned ng = ws[C_NG]; if (ng > CAPG) ng = CAPG;
    uint2* glist = (uint2*)(ws + GLIST_OFF);
    uint2* list2 = (uint2*)(ws + LIST2_OFF);
    const unsigned stride = gridDim.x * 256u;
    for (unsigned i = blockIdx.x * 256u + (unsigned)threadIdx.x; i < ng; i += stride) {
        uint2 e = glist[i];
        if (e.x >= winTh) out[e.y] = valOf(e.x);     // >= 2.0 > 0: relu moot
        else if (e.x >= candTh) {                    // cutoff bin (~190 total)
            unsigned g = atomicAdd(&ws[C_N2], 1u);
            if (g < CAP2) list2[g] = e;
        }
    }
}

// ---------------- tail + fallback merged (1 block, 1024 threads): fast path =
// exact rank among cutoff-bin candidates + EMA; else full exact fallback.
__global__ __launch_bounds__(1024) void k_tail(const float4* __restrict__ x,
                                               const int* __restrict__ mask,
                                               unsigned* __restrict__ ws,
                                               float* __restrict__ out,
                                               const float* __restrict__ thr) {
    // LDS union: tail ent[4096]uint2 + red[1024] | fb lh[4096]+sred[1024]
    __shared__ __align__(16) unsigned smem[9216];   // 36 KB
    __shared__ unsigned sB1, sKA, sMode, sNegmin, sB2, sNeed, sCnt;
    const int t = threadIdx.x;
    const unsigned rawn2 = ws[C_N2];
    const unsigned fb = ws[C_FB] | (rawn2 > CAP2 ? 1u : 0u);

    if (!fb) {
        // ---- fast tail: exact rank among cutoff-bin candidates + EMA threshold
        uint2* ent = (uint2*)smem;                 // [0, 8192) words
        unsigned* red = smem + 8192;               // [8192, 9216)
        const unsigned n2 = rawn2;
        const unsigned need = ws[C_NEED];          // >= 1 by crossing construction
        uint2* list2 = (uint2*)(ws + LIST2_OFF);
        for (unsigned i = (unsigned)t; i < n2; i += 1024u) ent[i] = list2[i];
        __syncthreads();
        unsigned minSel = 0xFFFFFFFFu;
        for (unsigned i = (unsigned)t; i < n2; i += 1024u) {
            uint2 e = ent[i];
            unsigned rank = 0u;
            for (unsigned j = 0; j < n2; ++j) {    // ties -> lower idx (jax.lax.top_k)
                uint2 o = ent[j];
                rank += (o.x > e.x || (o.x == e.x && o.y < e.y)) ? 1u : 0u;
            }
            if (rank < need) {
                out[e.y] = valOf(e.x);
                if (e.x < minSel) minSel = e.x;
            }
        }
        red[t] = minSel;
        __syncthreads();
        for (int off = 512; off > 0; off >>= 1) {
            if (t < off) red[t] = red[t] < red[t + off] ? red[t] : red[t + off];
            __syncthreads();
        }
        if (t == 0) {
            // fast path: min selected = k-th largest >= 2.0 > 0 == min_pos
            out[N_ELEMS] = 0.99f * thr[0] + 0.01f * valOf(red[0]);
        }
        return;
    }

    // ---- fallback: full exact algorithm (correctness-only; never runs for
    // this input — cutoff >= 2.0 with wide margin). Out zeros are already
    // present from k_stream's fill blocks.
    unsigned* lh = smem;               // [0, 4096): coarse 12-bit bins then reused
    unsigned* sred = smem + 4096;      // [4096, 5120)
    for (int b = t; b < NBINS; b += 1024) lh[b] = 0u;
    if (t == 0) sCnt = 0u;
    __syncthreads();
    unsigned negmin = 0u;              // max(~key) over positive values
    for (int tok = 0; tok < N_TOKENS; ++tok) {
        if (!mask[tok]) continue;
        const float4* xt = x + (size_t)tok * F4;
        for (int j = t; j < F4; j += 1024) {
            float4 v = xt[j];
            float fv[4] = {v.x, v.y, v.z, v.w};
            #pragma unroll
            for (int c = 0; c < 4; ++c) {
                float f = fv[c];
                unsigned u = keyOf(f);
                atomicAdd(&lh[u >> 20], 1u);
                if (f > 0.0f) negmin = umaxu(negmin, ~u);
            }
        }
    }
    __syncthreads();
    sred[t] = negmin; __syncthreads();
    for (int off = 512; off > 0; off >>= 1) {
        if (t < off) sred[t] = umaxu(sred[t], sred[t + off]);
        __syncthreads();
    }
    if (t == 0) {
        sNegmin = sred[0];
        unsigned tot = 0u;
        for (int b = 0; b < NBINS; ++b) tot += lh[b];
        if (tot <= K_TOTAL) sMode = 1u;          // select ALL unmasked elements
        else {
            sMode = 0u;
            unsigned run = 0u, prev = 0u; int b1 = 0;
            for (int b = NBINS - 1; b >= 0; --b) {
                prev = run; run += lh[b];
                if (run >= K_TOTAL && prev < K_TOTAL) { b1 = b; break; }
            }
            sB1 = (unsigned)b1; sKA = prev;
        }
        sCnt = 0u;
    }
    __syncthreads();
    if (sMode == 1u) {
        for (int tok = 0; tok < N_TOKENS; ++tok) {
            if (!mask[tok]) continue;
            const float4* xt = x + (size_t)tok * F4;
            float* ot = out + (size_t)tok * 16384;
            for (int j = t; j < F4; j += 1024) {
                float4 v = xt[j];
                ot[j * 4 + 0] = fmaxf(v.x, 0.f); ot[j * 4 + 1] = fmaxf(v.y, 0.f);
                ot[j * 4 + 2] = fmaxf(v.z, 0.f); ot[j * 4 + 3] = fmaxf(v.w, 0.f);
            }
        }
        if (t == 0) {
            float th = thr[0], newt = th;
            if (sNegmin) newt = 0.99f * th + 0.01f * valOf(~sNegmin);
            out[N_ELEMS] = newt;
        }
        return;
    }
    // phase 2: scatter coarse winners; compact coarse cutoff bin
    const unsigned B1c = sB1;
    uint2* fb1 = (uint2*)(ws + FB1_OFF);
    for (int tok = 0; tok < N_TOKENS; ++tok) {
        if (!mask[tok]) continue;
        const float4* xt = x + (size_t)tok * F4;
        const unsigned baseIdx = (unsigned)tok * 16384u;
        for (int j = t; j < F4; j += 1024) {
            float4 v = xt[j];
            float fv[4] = {v.x, v.y, v.z, v.w};
            #pragma unroll
            for (int c = 0; c < 4; ++c) {
                float f = fv[c];
                unsigned u = keyOf(f);
                unsigned p = u >> 20;
                unsigned idx = baseIdx + (unsigned)j * 4u + (unsigned)c;
                if (p > B1c) out[idx] = fmaxf(f, 0.f);
                else if (p == B1c) {
                    unsigned g = atomicAdd(&sCnt, 1u);
                    if (g < CAPF) fb1[g] = make_uint2(u, idx);
                }
            }
        }
    }
    __syncthreads();
    unsigned n1 = sCnt > CAPF ? CAPF : sCnt;
    __syncthreads();
    if (t < 256) lh[t] = 0u;           // reuse as 8-bit refine histogram
    if (t == 0) sCnt = 0u;
    __syncthreads();
    for (unsigned i = t; i < n1; i += 1024)
        atomicAdd(&lh[(fb1[i].x >> 12) & 255u], 1u);
    __syncthreads();
    if (t == 0) {
        unsigned run = sKA, prev = sKA; int b2 = 0;
        for (int b = 255; b >= 0; --b) {
            prev = run; run += lh[b];
            if (run >= K_TOTAL) { b2 = b; break; }
        }
        sB2 = (unsigned)b2; sNeed = K_TOTAL - prev;
    }
    __syncthreads();
    const unsigned B2 = sB2, need = sNeed;
    uint2* fb2 = (uint2*)(ws + FB2_OFF);
    for (unsigned i = t; i < n1; i += 1024) {
        uint2 e = fb1[i];
        unsigned bb = (e.x >> 12) & 255u;
        if (bb > B2) out[e.y] = fmaxf(valOf(e.x), 0.f);
        else if (bb == B2) {
            unsigned g = atomicAdd(&sCnt, 1u);
            if (g < CAPF) fb2[g] = e;
        }
    }
    __syncthreads();
    unsigned n2f = sCnt > CAPF ? CAPF : sCnt;
    unsigned minSel = 0xFFFFFFFFu;
    for (unsigned i = t; i < n2f; i += 1024) {
        uint2 e = fb2[i];
        unsigned rank = 0u;
        for (unsigned jj = 0; jj < n2f; ++jj) {
            uint2 o = fb2[jj];
            rank += (o.x > e.x || (o.x == e.x && o.y < e.y)) ? 1u : 0u;
        }
        if (rank < need) { out[e.y] = fmaxf(valOf(e.x), 0.f); if (e.x < minSel) minSel = e.x; }
    }
    __syncthreads();
    sred[t] = minSel; __syncthreads();
    for (int off = 512; off > 0; off >>= 1) {
        if (t < off) sred[t] = sred[t] < sred[t + off] ? sred[t] : sred[t + off];
        __syncthreads();
    }
    if (t == 0) {
        float th = thr[0], newt = th;
        unsigned vku = sred[0];
        if (vku != 0xFFFFFFFFu) {
            float vk = valOf(vku);
            float minpos; int any;
            if (vk > 0.f) { minpos = vk; any = 1; }
            else { any = (sNegmin != 0u); minpos = any ? valOf(~sNegmin) : 0.f; }
            if (any) newt = 0.99f * th + 0.01f * minpos;
        }
        out[N_ELEMS] = newt;
    }
}

extern "C" void kernel_launch(void* const* d_in, const int* in_sizes, int n_in,
                              void* d_out, int out_size, void* d_ws, size_t ws_size,
                              hipStream_t stream) {
    const float4* x  = (const float4*)d_in[0];
    const int* mask  = (const int*)d_in[1];
    const float* thr = (const float*)d_in[2];
    float* out       = (float*)d_out;
    unsigned* ws     = (unsigned*)d_ws;

    k_init    <<<17, 256, 0, stream>>>(ws);
    k_stream  <<<STREAM_BLOCKS, 512, 0, stream>>>(x, mask, ws, (float4*)out);
    k_scatter <<<512, 256, 0, stream>>>(ws, out);
    k_tail    <<<1, 1024, 0, stream>>>(x, mask, ws, out, thr);
}